// Round 1
// baseline (251.167 us; speedup 1.0000x reference)
//
#include <hip/hip_runtime.h>

// Problem constants (match reference file)
#define NUM_SRC 100000
#define NUM_DST 100000
#define NNZ     3200000
#define BATCH   16

// ---------------------------------------------------------------------------
// Kernel 1: transpose x (BATCH, NUM_SRC) -> xT (NUM_SRC, BATCH)
// reads coalesced across s for each b; writes 64B contiguous per thread.
// ---------------------------------------------------------------------------
__global__ void k_transpose_x(const float* __restrict__ x,
                              float* __restrict__ xT) {
    int s = blockIdx.x * blockDim.x + threadIdx.x;
    if (s >= NUM_SRC) return;
    float v[BATCH];
#pragma unroll
    for (int b = 0; b < BATCH; ++b)
        v[b] = x[(long)b * NUM_SRC + s];
    float4* dst = reinterpret_cast<float4*>(xT + (long)s * BATCH);
#pragma unroll
    for (int q = 0; q < 4; ++q)
        dst[q] = make_float4(v[4*q+0], v[4*q+1], v[4*q+2], v[4*q+3]);
}

// ---------------------------------------------------------------------------
// Kernel 2: edge scatter. One thread per (edge, batch) pair.
// tid = e*16 + b. xT load coalesced (16 lanes read one 64B line per edge),
// atomicAdd targets 16 consecutive floats per edge (one cacheline per row).
// ---------------------------------------------------------------------------
__global__ void k_edge_scatter(const float* __restrict__ values,
                               const int*  __restrict__ row,
                               const int*  __restrict__ col,
                               const float* __restrict__ xT,
                               float* __restrict__ outT) {
    long tid = (long)blockIdx.x * blockDim.x + threadIdx.x;
    long e = tid >> 4;
    int  b = (int)(tid & 15);
    if (e >= NNZ) return;
    int   r = row[e];
    int   c = col[e];
    float v = values[e];
    float xv = xT[(long)c * BATCH + b];
    atomicAdd(outT + (long)r * BATCH + b, v * xv);
}

// ---------------------------------------------------------------------------
// Kernel 3: finalize. outT (DST,16) + bias -> out (16,DST).
// Per-thread 64B coalesced read; 16 coalesced store streams (one per b).
// ---------------------------------------------------------------------------
__global__ void k_finalize(const float* __restrict__ outT,
                           const float* __restrict__ bias,
                           float* __restrict__ out) {
    int d = blockIdx.x * blockDim.x + threadIdx.x;
    if (d >= NUM_DST) return;
    float bv = bias[d];
    const float4* src = reinterpret_cast<const float4*>(outT + (long)d * BATCH);
    float acc[BATCH];
#pragma unroll
    for (int q = 0; q < 4; ++q) {
        float4 t = src[q];
        acc[4*q+0] = t.x; acc[4*q+1] = t.y; acc[4*q+2] = t.z; acc[4*q+3] = t.w;
    }
#pragma unroll
    for (int b = 0; b < BATCH; ++b)
        out[(long)b * NUM_DST + d] = acc[b] + bv;
}

extern "C" void kernel_launch(void* const* d_in, const int* in_sizes, int n_in,
                              void* d_out, int out_size, void* d_ws, size_t ws_size,
                              hipStream_t stream) {
    const float* x      = (const float*)d_in[0];  // (16, 100000) f32
    const float* values = (const float*)d_in[1];  // (3.2M,) f32
    const float* bias   = (const float*)d_in[2];  // (100000,) f32
    const int*   idx    = (const int*)  d_in[3];  // (2, 3.2M) int32: [row | col]
    const int* row = idx;
    const int* col = idx + NNZ;
    float* out = (float*)d_out;

    // workspace layout: xT (NUM_SRC*16 f32) | outT (NUM_DST*16 f32)
    float* xT   = (float*)d_ws;
    float* outT = xT + (long)NUM_SRC * BATCH;

    hipMemsetAsync(outT, 0, (size_t)NUM_DST * BATCH * sizeof(float), stream);

    {
        int threads = 256;
        int blocks = (NUM_SRC + threads - 1) / threads;
        k_transpose_x<<<blocks, threads, 0, stream>>>(x, xT);
    }
    {
        long total = (long)NNZ * BATCH;   // 51.2M threads
        int threads = 256;
        long blocks = (total + threads - 1) / threads;
        k_edge_scatter<<<(int)blocks, threads, 0, stream>>>(values, row, col, xT, outT);
    }
    {
        int threads = 256;
        int blocks = (NUM_DST + threads - 1) / threads;
        k_finalize<<<blocks, threads, 0, stream>>>(outT, bias, out);
    }
}